// Round 5
// baseline (581.345 us; speedup 1.0000x reference)
//
#include <hip/hip_runtime.h>
#include <hip/hip_fp16.h>

// ---------------------------------------------------------------------------
// GCN 3-layer forward. Feature-chunked L2-resident gather aggregation.
// H buffers chunk-major: H[c][i][f], c<8, f<16 (3.2 MB slice per XCD L2).
// Agg blocks pin chunk = blockIdx&7 (round-robin block->XCD).
// CSR entry = 4B packed (src<<16 | f16(norm)); CSR loads + agg output stores
// are non-temporal so streams don't evict the L2 slice.
// Wave per node: 16 edge-ways x 4 lanes (float4), 2x unroll = 32 edges in
// flight; shfl_xor reduction over ways.
//
// d_ws (4-byte units):
//   csr  [E]      packed uint
//   A    [N*128]  post-GEMM h (chunk-major)
//   B    [N*128]  layer output (chunk-major)
//   C    [N*16]   layer-3 post-GEMM (row-major = single chunk)
//   dinv [N]
//   offs [N+1]
//   cnt  [N]      (reused as fill cursor)
//   bsum [256]
// ---------------------------------------------------------------------------

typedef float f32x4 __attribute__((ext_vector_type(4)));

static inline int cdiv(int a, int b) { return (a + b - 1) / b; }

__global__ __launch_bounds__(256) void k_zero_int(int* p, int n) {
    int i = blockIdx.x * 256 + threadIdx.x;
    if (i < n) p[i] = 0;
}

__global__ __launch_bounds__(256) void k_count(const int* __restrict__ col, int* cnt, int e) {
    int i = blockIdx.x * 256 + threadIdx.x;
    if (i < e) atomicAdd(&cnt[col[i]], 1);
}

// per-256-chunk sums for scan; also computes dinv = rsqrt(deg+1)
__global__ __launch_bounds__(256) void k_scanA(const int* __restrict__ cnt, int* bsum,
                                               float* __restrict__ dinv, int n) {
    __shared__ int s[256];
    int t = threadIdx.x;
    int i = blockIdx.x * 256 + t;
    int v = (i < n) ? cnt[i] : 0;
    if (i < n) dinv[i] = rsqrtf((float)(v + 1));
    s[t] = v;
    __syncthreads();
    for (int off = 128; off > 0; off >>= 1) {
        if (t < off) s[t] += s[t + off];
        __syncthreads();
    }
    if (t == 0) bsum[blockIdx.x] = s[0];
}

__global__ __launch_bounds__(256) void k_scanB(int* bsum, int nb) {
    __shared__ int s[256];
    int t = threadIdx.x;
    int v = (t < nb) ? bsum[t] : 0;
    s[t] = v;
    for (int off = 1; off < 256; off <<= 1) {
        __syncthreads();
        int x = (t >= off) ? s[t - off] : 0;
        __syncthreads();
        s[t] += x;
    }
    __syncthreads();
    if (t < nb) bsum[t] = s[t] - v;
}

// per-chunk exclusive scan + block offset -> offs; also zeroes cursor
__global__ __launch_bounds__(256) void k_scanC(int* __restrict__ cnt, const int* __restrict__ bsum,
                                               int* offs, int n) {
    __shared__ int s[256];
    int t = threadIdx.x;
    int i = blockIdx.x * 256 + t;
    int v = (i < n) ? cnt[i] : 0;
    s[t] = v;
    for (int off = 1; off < 256; off <<= 1) {
        __syncthreads();
        int x = (t >= off) ? s[t - off] : 0;
        __syncthreads();
        s[t] += x;
    }
    __syncthreads();
    if (i <= n) offs[i] = bsum[blockIdx.x] + s[t] - v;
    if (i < n) cnt[i] = 0;
}

// csr[pos] = (src<<16) | f16(dinv[src]*dinv[dst])   (n < 65536)
__global__ __launch_bounds__(256) void k_fill(const int* __restrict__ row, const int* __restrict__ col,
                                              const float* __restrict__ dinv, const int* __restrict__ offs,
                                              int* cur, unsigned int* __restrict__ csr, int e) {
    int i = blockIdx.x * 256 + threadIdx.x;
    if (i >= e) return;
    int c = col[i], r = row[i];
    float w = dinv[r] * dinv[c];
    int pos = offs[c] + atomicAdd(&cur[c], 1);
    unsigned short hw = __half_as_ushort(__float2half_rn(w));
    csr[pos] = ((unsigned int)r << 16) | (unsigned int)hw;
}

// H(out, chunk-major)[n,128] = X[n,128] @ W[128,128]. CM_IN: X chunk-major.
template <bool CM_IN>
__global__ __launch_bounds__(256) void k_gemm128(const float* __restrict__ X, const float* __restrict__ W,
                                                 float* __restrict__ H, int n) {
    __shared__ float sW[128 * 128];
    __shared__ float sX[32 * 128];
    int tid = threadIdx.x;
    for (int i = tid; i < 4096; i += 256)
        ((float4*)sW)[i] = ((const float4*)W)[i];
    int row0 = blockIdx.x * 32;
    for (int i = tid; i < 1024; i += 256) {
        int r = i >> 5, f4 = i & 31;
        int gr = row0 + r;
        float4 v = make_float4(0.f, 0.f, 0.f, 0.f);
        if (gr < n) {
            size_t idx = CM_IN ? ((size_t)(f4 >> 2) * n * 4 + (size_t)gr * 4 + (f4 & 3))
                               : ((size_t)gr * 32 + f4);
            v = ((const float4*)X)[idx];
        }
        ((float4*)sX)[i] = v;
    }
    __syncthreads();

    int cg = tid & 31, rg = tid >> 5;
    float acc[4][4];
    #pragma unroll
    for (int i = 0; i < 4; ++i)
        #pragma unroll
        for (int j = 0; j < 4; ++j) acc[i][j] = 0.f;

    #pragma unroll 4
    for (int k = 0; k < 128; ++k) {
        float4 w4 = ((const float4*)sW)[k * 32 + cg];
        #pragma unroll
        for (int i = 0; i < 4; ++i) {
            float xv = sX[(rg * 4 + i) * 128 + k];
            acc[i][0] = fmaf(xv, w4.x, acc[i][0]);
            acc[i][1] = fmaf(xv, w4.y, acc[i][1]);
            acc[i][2] = fmaf(xv, w4.z, acc[i][2]);
            acc[i][3] = fmaf(xv, w4.w, acc[i][3]);
        }
    }
    int chunk = cg >> 2, w4i = cg & 3;
    #pragma unroll
    for (int i = 0; i < 4; ++i) {
        int gr = row0 + rg * 4 + i;
        if (gr < n)
            ((float4*)H)[(size_t)chunk * n * 4 + (size_t)gr * 4 + w4i] =
                make_float4(acc[i][0], acc[i][1], acc[i][2], acc[i][3]);
    }
}

// C(row-major)[n,16] = X(chunk-major)[n,128] @ W[128,16].
__global__ __launch_bounds__(256) void k_gemm16(const float* __restrict__ X, const float* __restrict__ W,
                                                float* __restrict__ H, int n) {
    __shared__ float sX[16 * 132];
    __shared__ float sW[128 * 16];
    int tid = threadIdx.x;
    for (int i = tid; i < 512; i += 256)
        ((float4*)sW)[i] = ((const float4*)W)[i];
    int row0 = blockIdx.x * 16;
    for (int i = tid; i < 512; i += 256) {
        int r = i >> 5, f4 = i & 31;
        int gr = row0 + r;
        float4 v = make_float4(0.f, 0.f, 0.f, 0.f);
        if (gr < n)
            v = ((const float4*)X)[(size_t)(f4 >> 2) * n * 4 + (size_t)gr * 4 + (f4 & 3)];
        *(float4*)&sX[r * 132 + f4 * 4] = v;
    }
    __syncthreads();

    int rl = tid >> 4, cj = tid & 15;
    float acc = 0.f;
    #pragma unroll 8
    for (int k = 0; k < 128; ++k)
        acc = fmaf(sX[rl * 132 + k], sW[k * 16 + cj], acc);
    int gr = row0 + rl;
    if (gr < n) H[(size_t)gr * 16 + cj] = acc;
}

// Chunked gather-aggregate. CSHIFT=3: 8 chunks (128-f layers); CSHIFT=0: 1 chunk (16-f).
// Wave per node: lane = 4*ew + s; ew in [0,16) edge-way, s = float4 within 16-f chunk.
// out[c][i][:] = relu( sum_e w_e*H[c][r_e][:] + dinv[i]^2*H[c][i][:] + b[c*16..] )
template <int CSHIFT>
__global__ __launch_bounds__(256) void k_aggc(const float* __restrict__ H, const unsigned int* __restrict__ csr,
                                              const int* __restrict__ offs, const float* __restrict__ dinv,
                                              const float* __restrict__ b, float* __restrict__ out, int n) {
    int chunk = blockIdx.x & ((1 << CSHIFT) - 1);
    int node  = ((blockIdx.x >> CSHIFT) << 2) + (threadIdx.x >> 6);
    if (node >= n) return;
    int lane = threadIdx.x & 63;
    int ew = lane >> 2, s = lane & 3;
    const f32x4* Hc = (const f32x4*)(H + (size_t)chunk * n * 16);
    int ed = offs[node], end = offs[node + 1];

    f32x4 acc = {0.f, 0.f, 0.f, 0.f};
    for (int base = ed; base < end; base += 32) {
        int i0 = base + ew, i1 = base + 16 + ew;
        unsigned int p0 = (i0 < end) ? __builtin_nontemporal_load(csr + i0) : 0u;
        unsigned int p1 = (i1 < end) ? __builtin_nontemporal_load(csr + i1) : 0u;
        float w0 = __half2float(__ushort_as_half((unsigned short)(p0 & 0xffffu)));
        float w1 = __half2float(__ushort_as_half((unsigned short)(p1 & 0xffffu)));
        f32x4 v0 = Hc[(size_t)(p0 >> 16) * 4 + s];
        f32x4 v1 = Hc[(size_t)(p1 >> 16) * 4 + s];
        acc += w0 * v0;
        acc += w1 * v1;
    }
    // reduce over the 16 edge-ways (strides 4,8,16,32)
    #pragma unroll
    for (int st = 4; st < 64; st <<= 1) {
        acc.x += __shfl_xor(acc.x, st);
        acc.y += __shfl_xor(acc.y, st);
        acc.z += __shfl_xor(acc.z, st);
        acc.w += __shfl_xor(acc.w, st);
    }
    if (ew == 0) {
        float dc = dinv[node], sl = dc * dc;
        f32x4 hv = Hc[(size_t)node * 4 + s];
        f32x4 bv = ((const f32x4*)b)[chunk * 4 + s];
        f32x4 o = acc + sl * hv + bv;
        o.x = fmaxf(o.x, 0.f);
        o.y = fmaxf(o.y, 0.f);
        o.z = fmaxf(o.z, 0.f);
        o.w = fmaxf(o.w, 0.f);
        __builtin_nontemporal_store(o, (f32x4*)(out + (size_t)chunk * n * 16) + (size_t)node * 4 + s);
    }
}

extern "C" void kernel_launch(void* const* d_in, const int* in_sizes, int n_in,
                              void* d_out, int out_size, void* d_ws, size_t ws_size,
                              hipStream_t stream) {
    const float* x  = (const float*)d_in[0];
    const int*   ei = (const int*)d_in[1];
    const float* W1 = (const float*)d_in[2];
    const float* b1 = (const float*)d_in[3];
    const float* W2 = (const float*)d_in[4];
    const float* b2 = (const float*)d_in[5];
    const float* W3 = (const float*)d_in[6];
    const float* b3 = (const float*)d_in[7];

    const int n = in_sizes[0] / 128;   // 50000 (< 65536, required by packed CSR)
    const int e = in_sizes[1] / 2;
    const int* row = ei;       // source j
    const int* col = ei + e;   // target i

    unsigned int* csr = (unsigned int*)d_ws;
    float* A    = (float*)(csr + e);
    float* B    = A + (size_t)n * 128;
    float* C    = B + (size_t)n * 128;
    float* dinv = C + (size_t)n * 16;
    int*   offs = (int*)(dinv + n);
    int*   cnt  = offs + (n + 1);
    int*   bsum = cnt + n;
    float* out  = (float*)d_out;

    const int nb = cdiv(n + 1, 256);

    // --- CSR build ---
    k_zero_int<<<cdiv(n, 256), 256, 0, stream>>>(cnt, n);
    k_count   <<<cdiv(e, 256), 256, 0, stream>>>(col, cnt, e);
    k_scanA   <<<nb, 256, 0, stream>>>(cnt, bsum, dinv, n);
    k_scanB   <<<1, 256, 0, stream>>>(bsum, nb);
    k_scanC   <<<nb, 256, 0, stream>>>(cnt, bsum, offs, n);
    k_fill    <<<cdiv(e, 256), 256, 0, stream>>>(row, col, dinv, offs, cnt, csr, e);

    const int aggGrid8 = 8 * cdiv(n, 4);
    const int aggGrid1 = cdiv(n, 4);

    // --- layer 1 ---
    k_gemm128<false><<<cdiv(n, 32), 256, 0, stream>>>(x, W1, A, n);
    k_aggc<3><<<aggGrid8, 256, 0, stream>>>(A, csr, offs, dinv, b1, B, n);
    // --- layer 2 ---
    k_gemm128<true><<<cdiv(n, 32), 256, 0, stream>>>(B, W2, A, n);
    k_aggc<3><<<aggGrid8, 256, 0, stream>>>(A, csr, offs, dinv, b2, B, n);
    // --- layer 3 ---
    k_gemm16<<<cdiv(n, 16), 256, 0, stream>>>(B, W3, C, n);
    k_aggc<0><<<aggGrid1, 256, 0, stream>>>(C, csr, offs, dinv, b3, out, n);
}

// Round 6
// 517.301 us; speedup vs baseline: 1.1238x; 1.1238x over previous
//
#include <hip/hip_runtime.h>
#include <hip/hip_fp16.h>

// ---------------------------------------------------------------------------
// GCN 3-layer forward. Feature-chunked L2-resident gather aggregation.
// H buffers chunk-major: H[c][i][f], c<8, f<16 (3.2 MB slice per XCD L2).
// Agg blocks pin chunk = blockIdx&7 (round-robin block->XCD).
// CSR entry = 4B packed (src<<16 | f16(norm)).
// Agg wave layout: 4 nodes x 4 edge-ways x 4 lanes (float4), 2x unroll
// = 8 edges/node/iter; 2-stage shfl reduction serves 4 nodes at once.
//
// d_ws (4-byte units):
//   csr  [E]      packed uint
//   A    [N*128]  post-GEMM h (chunk-major)
//   B    [N*128]  layer output (chunk-major)
//   C    [N*16]   layer-3 post-GEMM (row-major = single chunk)
//   dinv [N]
//   offs [N+1]
//   cnt  [N]      (reused as fill cursor)
//   bsum [256]
// ---------------------------------------------------------------------------

typedef float f32x4 __attribute__((ext_vector_type(4)));

static inline int cdiv(int a, int b) { return (a + b - 1) / b; }

__global__ __launch_bounds__(256) void k_zero_int(int* p, int n) {
    int i = blockIdx.x * 256 + threadIdx.x;
    if (i < n) p[i] = 0;
}

__global__ __launch_bounds__(256) void k_count(const int* __restrict__ col, int* cnt, int e) {
    int i = blockIdx.x * 256 + threadIdx.x;
    if (i < e) atomicAdd(&cnt[col[i]], 1);
}

// per-256-chunk sums for scan; also computes dinv = rsqrt(deg+1)
__global__ __launch_bounds__(256) void k_scanA(const int* __restrict__ cnt, int* bsum,
                                               float* __restrict__ dinv, int n) {
    __shared__ int s[256];
    int t = threadIdx.x;
    int i = blockIdx.x * 256 + t;
    int v = (i < n) ? cnt[i] : 0;
    if (i < n) dinv[i] = rsqrtf((float)(v + 1));
    s[t] = v;
    __syncthreads();
    for (int off = 128; off > 0; off >>= 1) {
        if (t < off) s[t] += s[t + off];
        __syncthreads();
    }
    if (t == 0) bsum[blockIdx.x] = s[0];
}

__global__ __launch_bounds__(256) void k_scanB(int* bsum, int nb) {
    __shared__ int s[256];
    int t = threadIdx.x;
    int v = (t < nb) ? bsum[t] : 0;
    s[t] = v;
    for (int off = 1; off < 256; off <<= 1) {
        __syncthreads();
        int x = (t >= off) ? s[t - off] : 0;
        __syncthreads();
        s[t] += x;
    }
    __syncthreads();
    if (t < nb) bsum[t] = s[t] - v;
}

// per-chunk exclusive scan + block offset -> offs; also zeroes cursor
__global__ __launch_bounds__(256) void k_scanC(int* __restrict__ cnt, const int* __restrict__ bsum,
                                               int* offs, int n) {
    __shared__ int s[256];
    int t = threadIdx.x;
    int i = blockIdx.x * 256 + t;
    int v = (i < n) ? cnt[i] : 0;
    s[t] = v;
    for (int off = 1; off < 256; off <<= 1) {
        __syncthreads();
        int x = (t >= off) ? s[t - off] : 0;
        __syncthreads();
        s[t] += x;
    }
    __syncthreads();
    if (i <= n) offs[i] = bsum[blockIdx.x] + s[t] - v;
    if (i < n) cnt[i] = 0;
}

// csr[pos] = (src<<16) | f16(dinv[src]*dinv[dst])   (n < 65536)
__global__ __launch_bounds__(256) void k_fill(const int* __restrict__ row, const int* __restrict__ col,
                                              const float* __restrict__ dinv, const int* __restrict__ offs,
                                              int* cur, unsigned int* __restrict__ csr, int e) {
    int i = blockIdx.x * 256 + threadIdx.x;
    if (i >= e) return;
    int c = col[i], r = row[i];
    float w = dinv[r] * dinv[c];
    int pos = offs[c] + atomicAdd(&cur[c], 1);
    unsigned short hw = __half_as_ushort(__float2half_rn(w));
    csr[pos] = ((unsigned int)r << 16) | (unsigned int)hw;
}

// H(out, chunk-major)[n,128] = X[n,128] @ W[128,128]. CM_IN: X chunk-major.
template <bool CM_IN>
__global__ __launch_bounds__(256) void k_gemm128(const float* __restrict__ X, const float* __restrict__ W,
                                                 float* __restrict__ H, int n) {
    __shared__ float sW[128 * 128];
    __shared__ float sX[32 * 128];
    int tid = threadIdx.x;
    for (int i = tid; i < 4096; i += 256)
        ((float4*)sW)[i] = ((const float4*)W)[i];
    int row0 = blockIdx.x * 32;
    for (int i = tid; i < 1024; i += 256) {
        int r = i >> 5, f4 = i & 31;
        int gr = row0 + r;
        float4 v = make_float4(0.f, 0.f, 0.f, 0.f);
        if (gr < n) {
            size_t idx = CM_IN ? ((size_t)(f4 >> 2) * n * 4 + (size_t)gr * 4 + (f4 & 3))
                               : ((size_t)gr * 32 + f4);
            v = ((const float4*)X)[idx];
        }
        ((float4*)sX)[i] = v;
    }
    __syncthreads();

    int cg = tid & 31, rg = tid >> 5;
    float acc[4][4];
    #pragma unroll
    for (int i = 0; i < 4; ++i)
        #pragma unroll
        for (int j = 0; j < 4; ++j) acc[i][j] = 0.f;

    #pragma unroll 4
    for (int k = 0; k < 128; ++k) {
        float4 w4 = ((const float4*)sW)[k * 32 + cg];
        #pragma unroll
        for (int i = 0; i < 4; ++i) {
            float xv = sX[(rg * 4 + i) * 128 + k];
            acc[i][0] = fmaf(xv, w4.x, acc[i][0]);
            acc[i][1] = fmaf(xv, w4.y, acc[i][1]);
            acc[i][2] = fmaf(xv, w4.z, acc[i][2]);
            acc[i][3] = fmaf(xv, w4.w, acc[i][3]);
        }
    }
    int chunk = cg >> 2, w4i = cg & 3;
    #pragma unroll
    for (int i = 0; i < 4; ++i) {
        int gr = row0 + rg * 4 + i;
        if (gr < n)
            ((float4*)H)[(size_t)chunk * n * 4 + (size_t)gr * 4 + w4i] =
                make_float4(acc[i][0], acc[i][1], acc[i][2], acc[i][3]);
    }
}

// C(row-major)[n,16] = X(chunk-major)[n,128] @ W[128,16].
__global__ __launch_bounds__(256) void k_gemm16(const float* __restrict__ X, const float* __restrict__ W,
                                                float* __restrict__ H, int n) {
    __shared__ float sX[16 * 132];
    __shared__ float sW[128 * 16];
    int tid = threadIdx.x;
    for (int i = tid; i < 512; i += 256)
        ((float4*)sW)[i] = ((const float4*)W)[i];
    int row0 = blockIdx.x * 16;
    for (int i = tid; i < 512; i += 256) {
        int r = i >> 5, f4 = i & 31;
        int gr = row0 + r;
        float4 v = make_float4(0.f, 0.f, 0.f, 0.f);
        if (gr < n)
            v = ((const float4*)X)[(size_t)(f4 >> 2) * n * 4 + (size_t)gr * 4 + (f4 & 3)];
        *(float4*)&sX[r * 132 + f4 * 4] = v;
    }
    __syncthreads();

    int rl = tid >> 4, cj = tid & 15;
    float acc = 0.f;
    #pragma unroll 8
    for (int k = 0; k < 128; ++k)
        acc = fmaf(sX[rl * 132 + k], sW[k * 16 + cj], acc);
    int gr = row0 + rl;
    if (gr < n) H[(size_t)gr * 16 + cj] = acc;
}

// Chunked gather-aggregate. CSHIFT=3: 8 chunks (128-f); CSHIFT=0: 1 chunk (16-f).
// Wave = 4 nodes x 4 edge-ways x 4 lanes(float4). 2x unroll -> 8 edges/node/iter.
// out[c][i][:] = relu( sum_e w_e*H[c][r_e][:] + dinv[i]^2*H[c][i][:] + b[c*16..] )
template <int CSHIFT>
__global__ __launch_bounds__(256) void k_aggc(const float* __restrict__ H, const unsigned int* __restrict__ csr,
                                              const int* __restrict__ offs, const float* __restrict__ dinv,
                                              const float* __restrict__ b, float* __restrict__ out, int n) {
    int chunk = blockIdx.x & ((1 << CSHIFT) - 1);
    int lane  = threadIdx.x & 63;
    int nsub  = lane >> 4;          // 0..3  node within wave
    int ew    = (lane >> 2) & 3;    // 0..3  edge-way
    int s     = lane & 3;           // float4 within 16-f chunk
    int node  = (((blockIdx.x >> CSHIFT) * 4 + (threadIdx.x >> 6)) << 2) + nsub;
    bool valid = node < n;
    int nd = valid ? node : (n - 1);
    const f32x4* Hc = (const f32x4*)(H + (size_t)chunk * n * 16);
    int ed = offs[nd], end = offs[nd + 1];
    if (!valid) end = ed;

    f32x4 acc = {0.f, 0.f, 0.f, 0.f};
    for (int base = ed; base < end; base += 8) {
        int i0 = base + ew, i1 = base + 4 + ew;
        unsigned int p0 = (i0 < end) ? __builtin_nontemporal_load(csr + i0) : 0u;
        unsigned int p1 = (i1 < end) ? __builtin_nontemporal_load(csr + i1) : 0u;
        float w0 = __half2float(__ushort_as_half((unsigned short)(p0 & 0xffffu)));
        float w1 = __half2float(__ushort_as_half((unsigned short)(p1 & 0xffffu)));
        f32x4 v0 = Hc[(size_t)(p0 >> 16) * 4 + s];
        f32x4 v1 = Hc[(size_t)(p1 >> 16) * 4 + s];
        acc += w0 * v0;
        acc += w1 * v1;
    }
    // reduce over the 4 edge-ways (strides 4, 8) — serves all 4 nodes at once
    #pragma unroll
    for (int st = 4; st < 16; st <<= 1) {
        acc.x += __shfl_xor(acc.x, st);
        acc.y += __shfl_xor(acc.y, st);
        acc.z += __shfl_xor(acc.z, st);
        acc.w += __shfl_xor(acc.w, st);
    }
    if (valid && ew == 0) {
        float dc = dinv[node], sl = dc * dc;
        f32x4 hv = Hc[(size_t)node * 4 + s];
        f32x4 bv = ((const f32x4*)b)[chunk * 4 + s];
        f32x4 o = acc + sl * hv + bv;
        o.x = fmaxf(o.x, 0.f);
        o.y = fmaxf(o.y, 0.f);
        o.z = fmaxf(o.z, 0.f);
        o.w = fmaxf(o.w, 0.f);
        __builtin_nontemporal_store(o, (f32x4*)(out + (size_t)chunk * n * 16) + (size_t)node * 4 + s);
    }
}

extern "C" void kernel_launch(void* const* d_in, const int* in_sizes, int n_in,
                              void* d_out, int out_size, void* d_ws, size_t ws_size,
                              hipStream_t stream) {
    const float* x  = (const float*)d_in[0];
    const int*   ei = (const int*)d_in[1];
    const float* W1 = (const float*)d_in[2];
    const float* b1 = (const float*)d_in[3];
    const float* W2 = (const float*)d_in[4];
    const float* b2 = (const float*)d_in[5];
    const float* W3 = (const float*)d_in[6];
    const float* b3 = (const float*)d_in[7];

    const int n = in_sizes[0] / 128;   // 50000 (< 65536, required by packed CSR)
    const int e = in_sizes[1] / 2;
    const int* row = ei;       // source j
    const int* col = ei + e;   // target i

    unsigned int* csr = (unsigned int*)d_ws;
    float* A    = (float*)(csr + e);
    float* B    = A + (size_t)n * 128;
    float* C    = B + (size_t)n * 128;
    float* dinv = C + (size_t)n * 16;
    int*   offs = (int*)(dinv + n);
    int*   cnt  = offs + (n + 1);
    int*   bsum = cnt + n;
    float* out  = (float*)d_out;

    const int nb = cdiv(n + 1, 256);

    // --- CSR build ---
    k_zero_int<<<cdiv(n, 256), 256, 0, stream>>>(cnt, n);
    k_count   <<<cdiv(e, 256), 256, 0, stream>>>(col, cnt, e);
    k_scanA   <<<nb, 256, 0, stream>>>(cnt, bsum, dinv, n);
    k_scanB   <<<1, 256, 0, stream>>>(bsum, nb);
    k_scanC   <<<nb, 256, 0, stream>>>(cnt, bsum, offs, n);
    k_fill    <<<cdiv(e, 256), 256, 0, stream>>>(row, col, dinv, offs, cnt, csr, e);

    const int aggGrid8 = 8 * cdiv(n, 16);   // 8 chunks x (16 nodes/block)
    const int aggGrid1 = cdiv(n, 16);

    // --- layer 1 ---
    k_gemm128<false><<<cdiv(n, 32), 256, 0, stream>>>(x, W1, A, n);
    k_aggc<3><<<aggGrid8, 256, 0, stream>>>(A, csr, offs, dinv, b1, B, n);
    // --- layer 2 ---
    k_gemm128<true><<<cdiv(n, 32), 256, 0, stream>>>(B, W2, A, n);
    k_aggc<3><<<aggGrid8, 256, 0, stream>>>(A, csr, offs, dinv, b2, B, n);
    // --- layer 3 ---
    k_gemm16<<<cdiv(n, 16), 256, 0, stream>>>(B, W3, C, n);
    k_aggc<0><<<aggGrid1, 256, 0, stream>>>(C, csr, offs, dinv, b3, out, n);
}

// Round 7
// 470.737 us; speedup vs baseline: 1.2350x; 1.0989x over previous
//
#include <hip/hip_runtime.h>
#include <hip/hip_fp16.h>

// ---------------------------------------------------------------------------
// GCN 3-layer forward. Row-major H everywhere; wide-row gather aggregation
// (R4 structure: wave/node, float4/lane, even-odd halves, 8 edges in flight).
// CSR entry = 4B packed (src<<16 | f16(norm)) — halves CSR stream vs int2.
// GEMM128: 128x128 tile, 8x8 micro-tile, W fully LDS-resident.
//
// d_ws (4-byte units):
//   csr  [E]     packed uint, grouped by dst
//   A    [N*128] post-GEMM h
//   B    [N*128] layer output
//   C    [N*16]  layer-3 post-GEMM
//   dinv [N]
//   offs [N+1]
//   cnt  [N]
//   cur  [N]     fill cursor (init = offs)
//   bsum [256]
// ---------------------------------------------------------------------------

static inline int cdiv(int a, int b) { return (a + b - 1) / b; }

__global__ __launch_bounds__(256) void k_zero_int(int* p, int n) {
    int i = blockIdx.x * 256 + threadIdx.x;
    if (i < n) p[i] = 0;
}

__global__ __launch_bounds__(256) void k_count(const int* __restrict__ col, int* cnt, int e) {
    int i = blockIdx.x * 256 + threadIdx.x;
    if (i < e) atomicAdd(&cnt[col[i]], 1);
}

// per-256-chunk sums for scan; also computes dinv = rsqrt(deg+1)
__global__ __launch_bounds__(256) void k_scanA(const int* __restrict__ cnt, int* bsum,
                                               float* __restrict__ dinv, int n) {
    __shared__ int s[256];
    int t = threadIdx.x;
    int i = blockIdx.x * 256 + t;
    int v = (i < n) ? cnt[i] : 0;
    if (i < n) dinv[i] = rsqrtf((float)(v + 1));
    s[t] = v;
    __syncthreads();
    for (int off = 128; off > 0; off >>= 1) {
        if (t < off) s[t] += s[t + off];
        __syncthreads();
    }
    if (t == 0) bsum[blockIdx.x] = s[0];
}

__global__ __launch_bounds__(256) void k_scanB(int* bsum, int nb) {
    __shared__ int s[256];
    int t = threadIdx.x;
    int v = (t < nb) ? bsum[t] : 0;
    s[t] = v;
    for (int off = 1; off < 256; off <<= 1) {
        __syncthreads();
        int x = (t >= off) ? s[t - off] : 0;
        __syncthreads();
        s[t] += x;
    }
    __syncthreads();
    if (t < nb) bsum[t] = s[t] - v;
}

// per-chunk exclusive scan + block offset -> offs; cursor copy for fill
__global__ __launch_bounds__(256) void k_scanC(const int* __restrict__ cnt, const int* __restrict__ bsum,
                                               int* offs, int* cur, int n) {
    __shared__ int s[256];
    int t = threadIdx.x;
    int i = blockIdx.x * 256 + t;
    int v = (i < n) ? cnt[i] : 0;
    s[t] = v;
    for (int off = 1; off < 256; off <<= 1) {
        __syncthreads();
        int x = (t >= off) ? s[t - off] : 0;
        __syncthreads();
        s[t] += x;
    }
    __syncthreads();
    int ov = bsum[blockIdx.x] + s[t] - v;
    if (i <= n) offs[i] = ov;
    if (i < n) cur[i] = ov;
}

// csr[pos] = (src<<16) | f16(dinv[src]*dinv[dst])   (n < 65536)
__global__ __launch_bounds__(256) void k_fill(const int* __restrict__ row, const int* __restrict__ col,
                                              const float* __restrict__ dinv, int* cur,
                                              unsigned int* __restrict__ csr, int e) {
    int i = blockIdx.x * 256 + threadIdx.x;
    if (i >= e) return;
    int c = col[i], r = row[i];
    float w = dinv[r] * dinv[c];
    int pos = atomicAdd(&cur[c], 1);
    unsigned short hw = __half_as_ushort(__float2half_rn(w));
    csr[pos] = ((unsigned int)r << 16) | (unsigned int)hw;
}

// H[n,128] = X[n,128] @ W[128,128]. 128-row tile, 8x8 micro-tile.
// LDS: sW [k][col] full 64 KB; sX [kk][row] transposed 16-k slice (8 KB).
__global__ __launch_bounds__(256) void k_gemm128(const float* __restrict__ X, const float* __restrict__ W,
                                                 float* __restrict__ H, int n) {
    __shared__ float sW[128 * 128];
    __shared__ float sX[16][128];
    int tid = threadIdx.x;
    for (int i = tid; i < 4096; i += 256)
        ((float4*)sW)[i] = ((const float4*)W)[i];

    int row0 = blockIdx.x * 128;
    int tx = tid & 15, ty = tid >> 4;
    float acc[8][8];
    #pragma unroll
    for (int i = 0; i < 8; ++i)
        #pragma unroll
        for (int j = 0; j < 8; ++j) acc[i][j] = 0.f;

    for (int k0 = 0; k0 < 128; k0 += 16) {
        __syncthreads();   // also covers initial sW load on first iteration
        // stage X[row0..+127][k0..+15] transposed: 512 float4, 2 per thread
        #pragma unroll
        for (int i = tid; i < 512; i += 256) {
            int r = i >> 2, kq = i & 3;
            int gr = row0 + r;
            float4 v = (gr < n) ? ((const float4*)X)[(size_t)gr * 32 + (k0 >> 2) + kq]
                                : make_float4(0.f, 0.f, 0.f, 0.f);
            sX[kq * 4 + 0][r] = v.x;
            sX[kq * 4 + 1][r] = v.y;
            sX[kq * 4 + 2][r] = v.z;
            sX[kq * 4 + 3][r] = v.w;
        }
        __syncthreads();
        #pragma unroll
        for (int kk = 0; kk < 16; ++kk) {
            float a[8], b[8];
            *(float4*)&a[0] = *(const float4*)&sX[kk][ty * 8];
            *(float4*)&a[4] = *(const float4*)&sX[kk][ty * 8 + 4];
            *(float4*)&b[0] = *(const float4*)&sW[(k0 + kk) * 128 + tx * 8];
            *(float4*)&b[4] = *(const float4*)&sW[(k0 + kk) * 128 + tx * 8 + 4];
            #pragma unroll
            for (int i = 0; i < 8; ++i)
                #pragma unroll
                for (int j = 0; j < 8; ++j)
                    acc[i][j] = fmaf(a[i], b[j], acc[i][j]);
        }
    }
    #pragma unroll
    for (int i = 0; i < 8; ++i) {
        int gr = row0 + ty * 8 + i;
        if (gr < n) {
            ((float4*)H)[(size_t)gr * 32 + tx * 2]     = make_float4(acc[i][0], acc[i][1], acc[i][2], acc[i][3]);
            ((float4*)H)[(size_t)gr * 32 + tx * 2 + 1] = make_float4(acc[i][4], acc[i][5], acc[i][6], acc[i][7]);
        }
    }
}

// C[n,16] = X[n,128] @ W[128,16].
__global__ __launch_bounds__(256) void k_gemm16(const float* __restrict__ X, const float* __restrict__ W,
                                                float* __restrict__ H, int n) {
    __shared__ float sX[16 * 132];
    __shared__ float sW[128 * 16];
    int tid = threadIdx.x;
    for (int i = tid; i < 512; i += 256)
        ((float4*)sW)[i] = ((const float4*)W)[i];
    int row0 = blockIdx.x * 16;
    for (int i = tid; i < 512; i += 256) {
        int r = i >> 5, c = i & 31;
        int gr = row0 + r;
        float4 v = (gr < n) ? ((const float4*)X)[(size_t)gr * 32 + c]
                            : make_float4(0.f, 0.f, 0.f, 0.f);
        *(float4*)&sX[r * 132 + c * 4] = v;
    }
    __syncthreads();

    int rl = tid >> 4, cj = tid & 15;
    float acc = 0.f;
    #pragma unroll 8
    for (int k = 0; k < 128; ++k)
        acc = fmaf(sX[rl * 132 + k], sW[k * 16 + cj], acc);
    int gr = row0 + rl;
    if (gr < n) H[(size_t)gr * 16 + cj] = acc;
}

// F=128 gather-aggregate: wave per node, float4/lane, even/odd edge halves,
// 4-way unroll (8 edges in flight). out = relu(agg + dinv^2*h + b).
__global__ __launch_bounds__(256) void k_agg128(const float* __restrict__ H, const unsigned int* __restrict__ csr,
                                                const int* __restrict__ offs, const float* __restrict__ dinv,
                                                const float* __restrict__ b, float* __restrict__ out, int n) {
    int node = (blockIdx.x * 256 + threadIdx.x) >> 6;
    if (node >= n) return;
    int lane = threadIdx.x & 63;
    int sub  = lane & 31;
    int half = lane >> 5;
    const float4* H4 = (const float4*)H;
    int ed = offs[node], end = offs[node + 1];
    float4 acc = make_float4(0.f, 0.f, 0.f, 0.f);

    for (; ed + 7 < end; ed += 8) {
        unsigned int p0 = csr[ed     + half];
        unsigned int p1 = csr[ed + 2 + half];
        unsigned int p2 = csr[ed + 4 + half];
        unsigned int p3 = csr[ed + 6 + half];
        float4 v0 = H4[(size_t)(p0 >> 16) * 32 + sub];
        float4 v1 = H4[(size_t)(p1 >> 16) * 32 + sub];
        float4 v2 = H4[(size_t)(p2 >> 16) * 32 + sub];
        float4 v3 = H4[(size_t)(p3 >> 16) * 32 + sub];
        float w0 = __half2float(__ushort_as_half((unsigned short)(p0 & 0xffffu)));
        float w1 = __half2float(__ushort_as_half((unsigned short)(p1 & 0xffffu)));
        float w2 = __half2float(__ushort_as_half((unsigned short)(p2 & 0xffffu)));
        float w3 = __half2float(__ushort_as_half((unsigned short)(p3 & 0xffffu)));
        acc.x = fmaf(w0, v0.x, acc.x); acc.y = fmaf(w0, v0.y, acc.y);
        acc.z = fmaf(w0, v0.z, acc.z); acc.w = fmaf(w0, v0.w, acc.w);
        acc.x = fmaf(w1, v1.x, acc.x); acc.y = fmaf(w1, v1.y, acc.y);
        acc.z = fmaf(w1, v1.z, acc.z); acc.w = fmaf(w1, v1.w, acc.w);
        acc.x = fmaf(w2, v2.x, acc.x); acc.y = fmaf(w2, v2.y, acc.y);
        acc.z = fmaf(w2, v2.z, acc.z); acc.w = fmaf(w2, v2.w, acc.w);
        acc.x = fmaf(w3, v3.x, acc.x); acc.y = fmaf(w3, v3.y, acc.y);
        acc.z = fmaf(w3, v3.z, acc.z); acc.w = fmaf(w3, v3.w, acc.w);
    }
    #pragma unroll
    for (int s = 0; s < 4; ++s) {          // tail: up to 7 edges
        int idx = ed + 2 * s + half;
        if (idx < end) {
            unsigned int p = csr[idx];
            float4 v = H4[(size_t)(p >> 16) * 32 + sub];
            float w = __half2float(__ushort_as_half((unsigned short)(p & 0xffffu)));
            acc.x = fmaf(w, v.x, acc.x); acc.y = fmaf(w, v.y, acc.y);
            acc.z = fmaf(w, v.z, acc.z); acc.w = fmaf(w, v.w, acc.w);
        }
    }
    acc.x += __shfl_xor(acc.x, 32);
    acc.y += __shfl_xor(acc.y, 32);
    acc.z += __shfl_xor(acc.z, 32);
    acc.w += __shfl_xor(acc.w, 32);

    float di = dinv[node], sl = di * di;
    float4 hv = H4[(size_t)node * 32 + sub];
    float4 bv = ((const float4*)b)[sub];
    float4 o;
    o.x = fmaxf(fmaf(sl, hv.x, acc.x) + bv.x, 0.f);
    o.y = fmaxf(fmaf(sl, hv.y, acc.y) + bv.y, 0.f);
    o.z = fmaxf(fmaf(sl, hv.z, acc.z) + bv.z, 0.f);
    o.w = fmaxf(fmaf(sl, hv.w, acc.w) + bv.w, 0.f);
    if (half == 0)
        ((float4*)out)[(size_t)node * 32 + sub] = o;
}

// F=16 gather-aggregate: 8 lanes per node (4 span row, even/odd halves).
__global__ __launch_bounds__(256) void k_agg16(const float* __restrict__ H, const unsigned int* __restrict__ csr,
                                               const int* __restrict__ offs, const float* __restrict__ dinv,
                                               const float* __restrict__ b, float* __restrict__ out, int n) {
    int t = blockIdx.x * 256 + threadIdx.x;
    int node = t >> 3;
    if (node >= n) return;
    int lane = t & 7;
    int sub  = lane & 3;
    int half = lane >> 2;
    const float4* H4 = (const float4*)H;
    int ed = offs[node], end = offs[node + 1];
    float4 acc = make_float4(0.f, 0.f, 0.f, 0.f);

    for (; ed + 3 < end; ed += 4) {
        unsigned int p0 = csr[ed     + half];
        unsigned int p1 = csr[ed + 2 + half];
        float4 v0 = H4[(size_t)(p0 >> 16) * 4 + sub];
        float4 v1 = H4[(size_t)(p1 >> 16) * 4 + sub];
        float w0 = __half2float(__ushort_as_half((unsigned short)(p0 & 0xffffu)));
        float w1 = __half2float(__ushort_as_half((unsigned short)(p1 & 0xffffu)));
        acc.x = fmaf(w0, v0.x, acc.x); acc.y = fmaf(w0, v0.y, acc.y);
        acc.z = fmaf(w0, v0.z, acc.z); acc.w = fmaf(w0, v0.w, acc.w);
        acc.x = fmaf(w1, v1.x, acc.x); acc.y = fmaf(w1, v1.y, acc.y);
        acc.z = fmaf(w1, v1.z, acc.z); acc.w = fmaf(w1, v1.w, acc.w);
    }
    #pragma unroll
    for (int s = 0; s < 2; ++s) {          // tail: up to 3 edges
        int idx = ed + 2 * s + half;
        if (idx < end) {
            unsigned int p = csr[idx];
            float4 v = H4[(size_t)(p >> 16) * 4 + sub];
            float w = __half2float(__ushort_as_half((unsigned short)(p & 0xffffu)));
            acc.x = fmaf(w, v.x, acc.x); acc.y = fmaf(w, v.y, acc.y);
            acc.z = fmaf(w, v.z, acc.z); acc.w = fmaf(w, v.w, acc.w);
        }
    }
    acc.x += __shfl_xor(acc.x, 4);
    acc.y += __shfl_xor(acc.y, 4);
    acc.z += __shfl_xor(acc.z, 4);
    acc.w += __shfl_xor(acc.w, 4);

    float di = dinv[node], sl = di * di;
    float4 hv = H4[(size_t)node * 4 + sub];
    float4 bv = ((const float4*)b)[sub];
    float4 o;
    o.x = fmaxf(fmaf(sl, hv.x, acc.x) + bv.x, 0.f);
    o.y = fmaxf(fmaf(sl, hv.y, acc.y) + bv.y, 0.f);
    o.z = fmaxf(fmaf(sl, hv.z, acc.z) + bv.z, 0.f);
    o.w = fmaxf(fmaf(sl, hv.w, acc.w) + bv.w, 0.f);
    if (half == 0)
        ((float4*)out)[(size_t)node * 4 + sub] = o;
}

extern "C" void kernel_launch(void* const* d_in, const int* in_sizes, int n_in,
                              void* d_out, int out_size, void* d_ws, size_t ws_size,
                              hipStream_t stream) {
    const float* x  = (const float*)d_in[0];
    const int*   ei = (const int*)d_in[1];
    const float* W1 = (const float*)d_in[2];
    const float* b1 = (const float*)d_in[3];
    const float* W2 = (const float*)d_in[4];
    const float* b2 = (const float*)d_in[5];
    const float* W3 = (const float*)d_in[6];
    const float* b3 = (const float*)d_in[7];

    const int n = in_sizes[0] / 128;   // 50000 (< 65536, required by packed CSR)
    const int e = in_sizes[1] / 2;
    const int* row = ei;       // source j
    const int* col = ei + e;   // target i

    unsigned int* csr = (unsigned int*)d_ws;
    float* A    = (float*)(csr + e);
    float* B    = A + (size_t)n * 128;
    float* C    = B + (size_t)n * 128;
    float* dinv = C + (size_t)n * 16;
    int*   offs = (int*)(dinv + n);
    int*   cnt  = offs + (n + 1);
    int*   cur  = cnt + n;
    int*   bsum = cur + n;
    float* out  = (float*)d_out;

    const int nb = cdiv(n + 1, 256);

    // --- CSR build ---
    k_zero_int<<<cdiv(n, 256), 256, 0, stream>>>(cnt, n);
    k_count   <<<cdiv(e, 256), 256, 0, stream>>>(col, cnt, e);
    k_scanA   <<<nb, 256, 0, stream>>>(cnt, bsum, dinv, n);
    k_scanB   <<<1, 256, 0, stream>>>(bsum, nb);
    k_scanC   <<<nb, 256, 0, stream>>>(cnt, bsum, offs, cur, n);
    k_fill    <<<cdiv(e, 256), 256, 0, stream>>>(row, col, dinv, cur, csr, e);

    // --- layer 1 ---
    k_gemm128<<<cdiv(n, 128), 256, 0, stream>>>(x, W1, A, n);
    k_agg128 <<<cdiv(n * 64, 256), 256, 0, stream>>>(A, csr, offs, dinv, b1, B, n);
    // --- layer 2 ---
    k_gemm128<<<cdiv(n, 128), 256, 0, stream>>>(B, W2, A, n);
    k_agg128 <<<cdiv(n * 64, 256), 256, 0, stream>>>(A, csr, offs, dinv, b2, B, n);
    // --- layer 3 ---
    k_gemm16 <<<cdiv(n, 16), 256, 0, stream>>>(B, W3, C, n);
    k_agg16  <<<cdiv(n * 8, 256), 256, 0, stream>>>(C, csr, offs, dinv, b3, out, n);
}

// Round 8
// 381.282 us; speedup vs baseline: 1.5247x; 1.2346x over previous
//
#include <hip/hip_runtime.h>
#include <hip/hip_fp16.h>

// ---------------------------------------------------------------------------
// GCN 3-layer forward. Gather-based CSR aggregation with f16 gather payloads.
// Post-GEMM h is stored ONLY as f16 (consumed only by agg: gather + self-loop);
// agg accumulates f32 and writes f32 layer output for the next GEMM.
// CSR entry = 4B packed (src<<16 | f16(norm)).
//
// d_ws (4-byte units):
//   csr  [E]     packed uint, grouped by dst
//   Ah   [N*64]  post-GEMM h as f16 (128 halves/row)
//   B    [N*128] layer output f32
//   Ch   [N*8]   layer-3 post-GEMM as f16 (16 halves/row)
//   dinv [N]
//   offs [N+1]
//   cnt  [N]
//   cur  [N]     fill cursor (init = offs)
//   bsum [256]
// ---------------------------------------------------------------------------

static inline int cdiv(int a, int b) { return (a + b - 1) / b; }

__global__ __launch_bounds__(256) void k_zero_int(int* p, int n) {
    int i = blockIdx.x * 256 + threadIdx.x;
    if (i < n) p[i] = 0;
}

__global__ __launch_bounds__(256) void k_count(const int* __restrict__ col, int* cnt, int e) {
    int i = blockIdx.x * 256 + threadIdx.x;
    if (i < e) atomicAdd(&cnt[col[i]], 1);
}

// per-256-chunk sums for scan; also computes dinv = rsqrt(deg+1)
__global__ __launch_bounds__(256) void k_scanA(const int* __restrict__ cnt, int* bsum,
                                               float* __restrict__ dinv, int n) {
    __shared__ int s[256];
    int t = threadIdx.x;
    int i = blockIdx.x * 256 + t;
    int v = (i < n) ? cnt[i] : 0;
    if (i < n) dinv[i] = rsqrtf((float)(v + 1));
    s[t] = v;
    __syncthreads();
    for (int off = 128; off > 0; off >>= 1) {
        if (t < off) s[t] += s[t + off];
        __syncthreads();
    }
    if (t == 0) bsum[blockIdx.x] = s[0];
}

__global__ __launch_bounds__(256) void k_scanB(int* bsum, int nb) {
    __shared__ int s[256];
    int t = threadIdx.x;
    int v = (t < nb) ? bsum[t] : 0;
    s[t] = v;
    for (int off = 1; off < 256; off <<= 1) {
        __syncthreads();
        int x = (t >= off) ? s[t - off] : 0;
        __syncthreads();
        s[t] += x;
    }
    __syncthreads();
    if (t < nb) bsum[t] = s[t] - v;
}

// per-chunk exclusive scan + block offset -> offs; cursor copy for fill
__global__ __launch_bounds__(256) void k_scanC(const int* __restrict__ cnt, const int* __restrict__ bsum,
                                               int* offs, int* cur, int n) {
    __shared__ int s[256];
    int t = threadIdx.x;
    int i = blockIdx.x * 256 + t;
    int v = (i < n) ? cnt[i] : 0;
    s[t] = v;
    for (int off = 1; off < 256; off <<= 1) {
        __syncthreads();
        int x = (t >= off) ? s[t - off] : 0;
        __syncthreads();
        s[t] += x;
    }
    __syncthreads();
    int ov = bsum[blockIdx.x] + s[t] - v;
    if (i <= n) offs[i] = ov;
    if (i < n) cur[i] = ov;
}

// csr[pos] = (src<<16) | f16(dinv[src]*dinv[dst])   (n < 65536)
__global__ __launch_bounds__(256) void k_fill(const int* __restrict__ row, const int* __restrict__ col,
                                              const float* __restrict__ dinv, int* cur,
                                              unsigned int* __restrict__ csr, int e) {
    int i = blockIdx.x * 256 + threadIdx.x;
    if (i >= e) return;
    int c = col[i], r = row[i];
    float w = dinv[r] * dinv[c];
    int pos = atomicAdd(&cur[c], 1);
    unsigned short hw = __half_as_ushort(__float2half_rn(w));
    csr[pos] = ((unsigned int)r << 16) | (unsigned int)hw;
}

// Ah[n,128](f16) = X[n,128](f32) @ W[128,128]. 128-row tile, 8x8 micro-tile.
__global__ __launch_bounds__(256) void k_gemm128(const float* __restrict__ X, const float* __restrict__ W,
                                                 __half* __restrict__ Ah, int n) {
    __shared__ float sW[128 * 128];
    __shared__ float sX[16][128];
    int tid = threadIdx.x;
    for (int i = tid; i < 4096; i += 256)
        ((float4*)sW)[i] = ((const float4*)W)[i];

    int row0 = blockIdx.x * 128;
    int tx = tid & 15, ty = tid >> 4;
    float acc[8][8];
    #pragma unroll
    for (int i = 0; i < 8; ++i)
        #pragma unroll
        for (int j = 0; j < 8; ++j) acc[i][j] = 0.f;

    for (int k0 = 0; k0 < 128; k0 += 16) {
        __syncthreads();
        #pragma unroll
        for (int i = tid; i < 512; i += 256) {
            int r = i >> 2, kq = i & 3;
            int gr = row0 + r;
            float4 v = (gr < n) ? ((const float4*)X)[(size_t)gr * 32 + (k0 >> 2) + kq]
                                : make_float4(0.f, 0.f, 0.f, 0.f);
            sX[kq * 4 + 0][r] = v.x;
            sX[kq * 4 + 1][r] = v.y;
            sX[kq * 4 + 2][r] = v.z;
            sX[kq * 4 + 3][r] = v.w;
        }
        __syncthreads();
        #pragma unroll
        for (int kk = 0; kk < 16; ++kk) {
            float a[8], b[8];
            *(float4*)&a[0] = *(const float4*)&sX[kk][ty * 8];
            *(float4*)&a[4] = *(const float4*)&sX[kk][ty * 8 + 4];
            *(float4*)&b[0] = *(const float4*)&sW[(k0 + kk) * 128 + tx * 8];
            *(float4*)&b[4] = *(const float4*)&sW[(k0 + kk) * 128 + tx * 8 + 4];
            #pragma unroll
            for (int i = 0; i < 8; ++i)
                #pragma unroll
                for (int j = 0; j < 8; ++j)
                    acc[i][j] = fmaf(a[i], b[j], acc[i][j]);
        }
    }
    #pragma unroll
    for (int i = 0; i < 8; ++i) {
        int gr = row0 + ty * 8 + i;
        if (gr < n) {
            union { uint4 u; __half2 h[4]; } pk;
            pk.h[0] = __floats2half2_rn(acc[i][0], acc[i][1]);
            pk.h[1] = __floats2half2_rn(acc[i][2], acc[i][3]);
            pk.h[2] = __floats2half2_rn(acc[i][4], acc[i][5]);
            pk.h[3] = __floats2half2_rn(acc[i][6], acc[i][7]);
            ((uint4*)Ah)[(size_t)gr * 16 + tx] = pk.u;   // cols tx*8..+7
        }
    }
}

// Ch[n,16](f16) = X[n,128](f32) @ W[128,16].
__global__ __launch_bounds__(256) void k_gemm16(const float* __restrict__ X, const float* __restrict__ W,
                                                __half* __restrict__ Ch, int n) {
    __shared__ float sX[16 * 132];
    __shared__ float sW[128 * 16];
    int tid = threadIdx.x;
    for (int i = tid; i < 512; i += 256)
        ((float4*)sW)[i] = ((const float4*)W)[i];
    int row0 = blockIdx.x * 16;
    for (int i = tid; i < 512; i += 256) {
        int r = i >> 5, c = i & 31;
        int gr = row0 + r;
        float4 v = (gr < n) ? ((const float4*)X)[(size_t)gr * 32 + c]
                            : make_float4(0.f, 0.f, 0.f, 0.f);
        *(float4*)&sX[r * 132 + c * 4] = v;
    }
    __syncthreads();

    int rl = tid >> 4, cj = tid & 15;
    float acc = 0.f;
    #pragma unroll 8
    for (int k = 0; k < 128; ++k)
        acc = fmaf(sX[rl * 132 + k], sW[k * 16 + cj], acc);
    int gr = row0 + rl;
    if (gr < n) Ch[(size_t)gr * 16 + cj] = __float2half_rn(acc);
}

// F=128 gather-aggregate from f16 H: wave per node, 4 halves (8B)/lane,
// even/odd edge halves, 4-way unroll (8 edges in flight). f32 accumulate.
__global__ __launch_bounds__(256) void k_agg128(const __half* __restrict__ Hh, const unsigned int* __restrict__ csr,
                                                const int* __restrict__ offs, const float* __restrict__ dinv,
                                                const float* __restrict__ b, float* __restrict__ out, int n) {
    int node = (blockIdx.x * 256 + threadIdx.x) >> 6;
    if (node >= n) return;
    int lane = threadIdx.x & 63;
    int sub  = lane & 31;     // uint2 (4 halves) within the 128-f row
    int half = lane >> 5;     // 0: even edges, 1: odd edges
    const uint2* H2 = (const uint2*)Hh;   // row stride = 32 uint2
    int ed = offs[node], end = offs[node + 1];
    float4 acc = make_float4(0.f, 0.f, 0.f, 0.f);

    #define EDGE_FMA(P)                                                          \
        {                                                                        \
            uint2 q = H2[(size_t)((P) >> 16) * 32 + sub];                        \
            float w = __half2float(__ushort_as_half((unsigned short)((P) & 0xffffu))); \
            float2 f01 = __half22float2(*(const __half2*)&q.x);                  \
            float2 f23 = __half22float2(*(const __half2*)&q.y);                  \
            acc.x = fmaf(w, f01.x, acc.x); acc.y = fmaf(w, f01.y, acc.y);        \
            acc.z = fmaf(w, f23.x, acc.z); acc.w = fmaf(w, f23.y, acc.w);        \
        }

    for (; ed + 7 < end; ed += 8) {
        unsigned int p0 = csr[ed     + half];
        unsigned int p1 = csr[ed + 2 + half];
        unsigned int p2 = csr[ed + 4 + half];
        unsigned int p3 = csr[ed + 6 + half];
        EDGE_FMA(p0); EDGE_FMA(p1); EDGE_FMA(p2); EDGE_FMA(p3);
    }
    #pragma unroll
    for (int s = 0; s < 4; ++s) {          // tail: up to 7 edges
        int idx = ed + 2 * s + half;
        if (idx < end) {
            unsigned int p = csr[idx];
            EDGE_FMA(p);
        }
    }
    #undef EDGE_FMA

    acc.x += __shfl_xor(acc.x, 32);
    acc.y += __shfl_xor(acc.y, 32);
    acc.z += __shfl_xor(acc.z, 32);
    acc.w += __shfl_xor(acc.w, 32);

    float di = dinv[node], sl = di * di;
    uint2 qh = H2[(size_t)node * 32 + sub];
    float2 h01 = __half22float2(*(const __half2*)&qh.x);
    float2 h23 = __half22float2(*(const __half2*)&qh.y);
    float4 bv = ((const float4*)b)[sub];
    float4 o;
    o.x = fmaxf(fmaf(sl, h01.x, acc.x) + bv.x, 0.f);
    o.y = fmaxf(fmaf(sl, h01.y, acc.y) + bv.y, 0.f);
    o.z = fmaxf(fmaf(sl, h23.x, acc.z) + bv.z, 0.f);
    o.w = fmaxf(fmaf(sl, h23.y, acc.w) + bv.w, 0.f);
    if (half == 0)
        ((float4*)out)[(size_t)node * 32 + sub] = o;
}

// F=16 gather-aggregate from f16 C: 8 lanes/node (4 x uint2, even/odd halves).
__global__ __launch_bounds__(256) void k_agg16(const __half* __restrict__ Ch, const unsigned int* __restrict__ csr,
                                               const int* __restrict__ offs, const float* __restrict__ dinv,
                                               const float* __restrict__ b, float* __restrict__ out, int n) {
    int t = blockIdx.x * 256 + threadIdx.x;
    int node = t >> 3;
    if (node >= n) return;
    int lane = t & 7;
    int sub  = lane & 3;      // uint2 (4 halves) within the 16-f row
    int half = lane >> 2;
    const uint2* C2 = (const uint2*)Ch;   // row stride = 4 uint2
    int ed = offs[node], end = offs[node + 1];
    float4 acc = make_float4(0.f, 0.f, 0.f, 0.f);

    #define EDGE_FMA16(P)                                                        \
        {                                                                        \
            uint2 q = C2[(size_t)((P) >> 16) * 4 + sub];                         \
            float w = __half2float(__ushort_as_half((unsigned short)((P) & 0xffffu))); \
            float2 f01 = __half22float2(*(const __half2*)&q.x);                  \
            float2 f23 = __half22float2(*(const __half2*)&q.y);                  \
            acc.x = fmaf(w, f01.x, acc.x); acc.y = fmaf(w, f01.y, acc.y);        \
            acc.z = fmaf(w, f23.x, acc.z); acc.w = fmaf(w, f23.y, acc.w);        \
        }

    for (; ed + 3 < end; ed += 4) {
        unsigned int p0 = csr[ed     + half];
        unsigned int p1 = csr[ed + 2 + half];
        EDGE_FMA16(p0); EDGE_FMA16(p1);
    }
    #pragma unroll
    for (int s = 0; s < 2; ++s) {          // tail: up to 3 edges
        int idx = ed + 2 * s + half;
        if (idx < end) {
            unsigned int p = csr[idx];
            EDGE_FMA16(p);
        }
    }
    #undef EDGE_FMA16

    acc.x += __shfl_xor(acc.x, 4);
    acc.y += __shfl_xor(acc.y, 4);
    acc.z += __shfl_xor(acc.z, 4);
    acc.w += __shfl_xor(acc.w, 4);

    float di = dinv[node], sl = di * di;
    uint2 qh = C2[(size_t)node * 4 + sub];
    float2 h01 = __half22float2(*(const __half2*)&qh.x);
    float2 h23 = __half22float2(*(const __half2*)&qh.y);
    float4 bv = ((const float4*)b)[sub];
    float4 o;
    o.x = fmaxf(fmaf(sl, h01.x, acc.x) + bv.x, 0.f);
    o.y = fmaxf(fmaf(sl, h01.y, acc.y) + bv.y, 0.f);
    o.z = fmaxf(fmaf(sl, h23.x, acc.z) + bv.z, 0.f);
    o.w = fmaxf(fmaf(sl, h23.y, acc.w) + bv.w, 0.f);
    if (half == 0)
        ((float4*)out)[(size_t)node * 4 + sub] = o;
}

extern "C" void kernel_launch(void* const* d_in, const int* in_sizes, int n_in,
                              void* d_out, int out_size, void* d_ws, size_t ws_size,
                              hipStream_t stream) {
    const float* x  = (const float*)d_in[0];
    const int*   ei = (const int*)d_in[1];
    const float* W1 = (const float*)d_in[2];
    const float* b1 = (const float*)d_in[3];
    const float* W2 = (const float*)d_in[4];
    const float* b2 = (const float*)d_in[5];
    const float* W3 = (const float*)d_in[6];
    const float* b3 = (const float*)d_in[7];

    const int n = in_sizes[0] / 128;   // 50000 (< 65536, required by packed CSR)
    const int e = in_sizes[1] / 2;
    const int* row = ei;       // source j
    const int* col = ei + e;   // target i

    unsigned int* csr = (unsigned int*)d_ws;
    __half* Ah  = (__half*)(csr + e);
    float*  B   = (float*)(Ah + (size_t)n * 128);
    __half* Ch  = (__half*)(B + (size_t)n * 128);
    float* dinv = (float*)(Ch + (size_t)n * 16);
    int*   offs = (int*)(dinv + n);
    int*   cnt  = offs + (n + 1);
    int*   cur  = cnt + n;
    int*   bsum = cur + n;
    float* out  = (float*)d_out;

    const int nb = cdiv(n + 1, 256);

    // --- CSR build ---
    k_zero_int<<<cdiv(n, 256), 256, 0, stream>>>(cnt, n);
    k_count   <<<cdiv(e, 256), 256, 0, stream>>>(col, cnt, e);
    k_scanA   <<<nb, 256, 0, stream>>>(cnt, bsum, dinv, n);
    k_scanB   <<<1, 256, 0, stream>>>(bsum, nb);
    k_scanC   <<<nb, 256, 0, stream>>>(cnt, bsum, offs, cur, n);
    k_fill    <<<cdiv(e, 256), 256, 0, stream>>>(row, col, dinv, cur, csr, e);

    // --- layer 1 ---
    k_gemm128<<<cdiv(n, 128), 256, 0, stream>>>(x, W1, Ah, n);
    k_agg128 <<<cdiv(n * 64, 256), 256, 0, stream>>>(Ah, csr, offs, dinv, b1, B, n);
    // --- layer 2 ---
    k_gemm128<<<cdiv(n, 128), 256, 0, stream>>>(B, W2, Ah, n);
    k_agg128 <<<cdiv(n * 64, 256), 256, 0, stream>>>(Ah, csr, offs, dinv, b2, B, n);
    // --- layer 3 ---
    k_gemm16 <<<cdiv(n, 16), 256, 0, stream>>>(B, W3, Ch, n);
    k_agg16  <<<cdiv(n * 8, 256), 256, 0, stream>>>(Ch, csr, offs, dinv, b3, out, n);
}

// Round 9
// 367.626 us; speedup vs baseline: 1.5814x; 1.0371x over previous
//
#include <hip/hip_runtime.h>
#include <hip/hip_fp16.h>

// ---------------------------------------------------------------------------
// GCN 3-layer forward. Gather-based CSR aggregation with f16 gather payloads.
// CSR fill is XCD-partitioned: 8 destination ranges, blocks pinned by
// blockIdx&7; each XCD's CSR writes stay in a 0.8 MB L2-resident slice so
// 4B scattered writes combine into full lines (vs 64B/edge write-through).
//
// d_ws (4-byte units):
//   csr  [E]     packed uint (src<<16 | f16(norm)), grouped by dst
//   Ah   [N*64]  post-GEMM h as f16 (128 halves/row)
//   B    [N*128] layer output f32
//   Ch   [N*8]   layer-3 post-GEMM as f16
//   dinv [N]
//   offs [N+1]
//   cnt  [N]
//   cur  [N]     fill cursor (init = offs)
//   bsum [256]
// ---------------------------------------------------------------------------

static inline int cdiv(int a, int b) { return (a + b - 1) / b; }

__global__ __launch_bounds__(256) void k_zero_int(int* p, int n) {
    int i = blockIdx.x * 256 + threadIdx.x;
    if (i < n) p[i] = 0;
}

__global__ __launch_bounds__(256) void k_count(const int* __restrict__ col, int* cnt, int e) {
    int i = blockIdx.x * 256 + threadIdx.x;
    if (i < e) atomicAdd(&cnt[col[i]], 1);
}

// per-256-chunk sums for scan; also computes dinv = rsqrt(deg+1)
__global__ __launch_bounds__(256) void k_scanA(const int* __restrict__ cnt, int* bsum,
                                               float* __restrict__ dinv, int n) {
    __shared__ int s[256];
    int t = threadIdx.x;
    int i = blockIdx.x * 256 + t;
    int v = (i < n) ? cnt[i] : 0;
    if (i < n) dinv[i] = rsqrtf((float)(v + 1));
    s[t] = v;
    __syncthreads();
    for (int off = 128; off > 0; off >>= 1) {
        if (t < off) s[t] += s[t + off];
        __syncthreads();
    }
    if (t == 0) bsum[blockIdx.x] = s[0];
}

__global__ __launch_bounds__(256) void k_scanB(int* bsum, int nb) {
    __shared__ int s[256];
    int t = threadIdx.x;
    int v = (t < nb) ? bsum[t] : 0;
    s[t] = v;
    for (int off = 1; off < 256; off <<= 1) {
        __syncthreads();
        int x = (t >= off) ? s[t - off] : 0;
        __syncthreads();
        s[t] += x;
    }
    __syncthreads();
    if (t < nb) bsum[t] = s[t] - v;
}

// per-chunk exclusive scan + block offset -> offs; cursor copy for fill
__global__ __launch_bounds__(256) void k_scanC(const int* __restrict__ cnt, const int* __restrict__ bsum,
                                               int* offs, int* cur, int n) {
    __shared__ int s[256];
    int t = threadIdx.x;
    int i = blockIdx.x * 256 + t;
    int v = (i < n) ? cnt[i] : 0;
    s[t] = v;
    for (int off = 1; off < 256; off <<= 1) {
        __syncthreads();
        int x = (t >= off) ? s[t - off] : 0;
        __syncthreads();
        s[t] += x;
    }
    __syncthreads();
    int ov = bsum[blockIdx.x] + s[t] - v;
    if (i <= n) offs[i] = ov;
    if (i < n) cur[i] = ov;
}

// XCD-partitioned fill: range g = blockIdx&7 owns dst in [g*rs, g*rs+rs).
// All csr/cur writes from one XCD land in its 1/8 slice -> L2 write combining.
__global__ __launch_bounds__(256) void k_fill_xcd(const int* __restrict__ row, const int* __restrict__ col,
                                                  const float* __restrict__ dinv, int* cur,
                                                  unsigned int* __restrict__ csr, int e, int n, int nblk) {
    int g = blockIdx.x & 7;
    int b = blockIdx.x >> 3;
    int rs = (n + 7) >> 3;
    int lo = g * rs;
    int hi = min(lo + rs, n);
    int stride = nblk * 256;
    for (int i = b * 256 + threadIdx.x; i < e; i += stride) {
        int c = col[i];
        if (c >= lo && c < hi) {
            int r = row[i];
            float w = dinv[r] * dinv[c];
            int pos = atomicAdd(&cur[c], 1);
            unsigned short hw = __half_as_ushort(__float2half_rn(w));
            csr[pos] = ((unsigned int)r << 16) | (unsigned int)hw;
        }
    }
}

// Ah[n,128](f16) = X[n,128](f32) @ W[128,128]. 128-row tile, 8x8 micro-tile.
__global__ __launch_bounds__(256) void k_gemm128(const float* __restrict__ X, const float* __restrict__ W,
                                                 __half* __restrict__ Ah, int n) {
    __shared__ float sW[128 * 128];
    __shared__ float sX[16][128];
    int tid = threadIdx.x;
    for (int i = tid; i < 4096; i += 256)
        ((float4*)sW)[i] = ((const float4*)W)[i];

    int row0 = blockIdx.x * 128;
    int tx = tid & 15, ty = tid >> 4;
    float acc[8][8];
    #pragma unroll
    for (int i = 0; i < 8; ++i)
        #pragma unroll
        for (int j = 0; j < 8; ++j) acc[i][j] = 0.f;

    for (int k0 = 0; k0 < 128; k0 += 16) {
        __syncthreads();
        #pragma unroll
        for (int i = tid; i < 512; i += 256) {
            int r = i >> 2, kq = i & 3;
            int gr = row0 + r;
            float4 v = (gr < n) ? ((const float4*)X)[(size_t)gr * 32 + (k0 >> 2) + kq]
                                : make_float4(0.f, 0.f, 0.f, 0.f);
            sX[kq * 4 + 0][r] = v.x;
            sX[kq * 4 + 1][r] = v.y;
            sX[kq * 4 + 2][r] = v.z;
            sX[kq * 4 + 3][r] = v.w;
        }
        __syncthreads();
        #pragma unroll
        for (int kk = 0; kk < 16; ++kk) {
            float a[8], b[8];
            *(float4*)&a[0] = *(const float4*)&sX[kk][ty * 8];
            *(float4*)&a[4] = *(const float4*)&sX[kk][ty * 8 + 4];
            *(float4*)&b[0] = *(const float4*)&sW[(k0 + kk) * 128 + tx * 8];
            *(float4*)&b[4] = *(const float4*)&sW[(k0 + kk) * 128 + tx * 8 + 4];
            #pragma unroll
            for (int i = 0; i < 8; ++i)
                #pragma unroll
                for (int j = 0; j < 8; ++j)
                    acc[i][j] = fmaf(a[i], b[j], acc[i][j]);
        }
    }
    #pragma unroll
    for (int i = 0; i < 8; ++i) {
        int gr = row0 + ty * 8 + i;
        if (gr < n) {
            union { uint4 u; __half2 h[4]; } pk;
            pk.h[0] = __floats2half2_rn(acc[i][0], acc[i][1]);
            pk.h[1] = __floats2half2_rn(acc[i][2], acc[i][3]);
            pk.h[2] = __floats2half2_rn(acc[i][4], acc[i][5]);
            pk.h[3] = __floats2half2_rn(acc[i][6], acc[i][7]);
            ((uint4*)Ah)[(size_t)gr * 16 + tx] = pk.u;   // cols tx*8..+7
        }
    }
}

// Ch[n,16](f16) = X[n,128](f32) @ W[128,16].
__global__ __launch_bounds__(256) void k_gemm16(const float* __restrict__ X, const float* __restrict__ W,
                                                __half* __restrict__ Ch, int n) {
    __shared__ float sX[16 * 132];
    __shared__ float sW[128 * 16];
    int tid = threadIdx.x;
    for (int i = tid; i < 512; i += 256)
        ((float4*)sW)[i] = ((const float4*)W)[i];
    int row0 = blockIdx.x * 16;
    for (int i = tid; i < 512; i += 256) {
        int r = i >> 5, c = i & 31;
        int gr = row0 + r;
        float4 v = (gr < n) ? ((const float4*)X)[(size_t)gr * 32 + c]
                            : make_float4(0.f, 0.f, 0.f, 0.f);
        *(float4*)&sX[r * 132 + c * 4] = v;
    }
    __syncthreads();

    int rl = tid >> 4, cj = tid & 15;
    float acc = 0.f;
    #pragma unroll 8
    for (int k = 0; k < 128; ++k)
        acc = fmaf(sX[rl * 132 + k], sW[k * 16 + cj], acc);
    int gr = row0 + rl;
    if (gr < n) Ch[(size_t)gr * 16 + cj] = __float2half_rn(acc);
}

// F=128 gather-aggregate from f16 H: wave per node, 4 halves (8B)/lane,
// even/odd edge halves, 4-way unroll (8 edges in flight). f32 accumulate.
__global__ __launch_bounds__(256) void k_agg128(const __half* __restrict__ Hh, const unsigned int* __restrict__ csr,
                                                const int* __restrict__ offs, const float* __restrict__ dinv,
                                                const float* __restrict__ b, float* __restrict__ out, int n) {
    int node = (blockIdx.x * 256 + threadIdx.x) >> 6;
    if (node >= n) return;
    int lane = threadIdx.x & 63;
    int sub  = lane & 31;     // uint2 (4 halves) within the 128-f row
    int half = lane >> 5;     // 0: even edges, 1: odd edges
    const uint2* H2 = (const uint2*)Hh;   // row stride = 32 uint2
    int ed = offs[node], end = offs[node + 1];
    float4 acc = make_float4(0.f, 0.f, 0.f, 0.f);

    #define EDGE_FMA(P)                                                          \
        {                                                                        \
            uint2 q = H2[(size_t)((P) >> 16) * 32 + sub];                        \
            float w = __half2float(__ushort_as_half((unsigned short)((P) & 0xffffu))); \
            float2 f01 = __half22float2(*(const __half2*)&q.x);                  \
            float2 f23 = __half22float2(*(const __half2*)&q.y);                  \
            acc.x = fmaf(w, f01.x, acc.x); acc.y = fmaf(w, f01.y, acc.y);        \
            acc.z = fmaf(w, f23.x, acc.z); acc.w = fmaf(w, f23.y, acc.w);        \
        }

    for (; ed + 7 < end; ed += 8) {
        unsigned int p0 = csr[ed     + half];
        unsigned int p1 = csr[ed + 2 + half];
        unsigned int p2 = csr[ed + 4 + half];
        unsigned int p3 = csr[ed + 6 + half];
        EDGE_FMA(p0); EDGE_FMA(p1); EDGE_FMA(p2); EDGE_FMA(p3);
    }
    #pragma unroll
    for (int s = 0; s < 4; ++s) {          // tail: up to 7 edges
        int idx = ed + 2 * s + half;
        if (idx < end) {
            unsigned int p = csr[idx];
            EDGE_FMA(p);
        }
    }
    #undef EDGE_FMA

    acc.x += __shfl_xor(acc.x, 32);
    acc.y += __shfl_xor(acc.y, 32);
    acc.z += __shfl_xor(acc.z, 32);
    acc.w += __shfl_xor(acc.w, 32);

    float di = dinv[node], sl = di * di;
    uint2 qh = H2[(size_t)node * 32 + sub];
    float2 h01 = __half22float2(*(const __half2*)&qh.x);
    float2 h23 = __half22float2(*(const __half2*)&qh.y);
    float4 bv = ((const float4*)b)[sub];
    float4 o;
    o.x = fmaxf(fmaf(sl, h01.x, acc.x) + bv.x, 0.f);
    o.y = fmaxf(fmaf(sl, h01.y, acc.y) + bv.y, 0.f);
    o.z = fmaxf(fmaf(sl, h23.x, acc.z) + bv.z, 0.f);
    o.w = fmaxf(fmaf(sl, h23.y, acc.w) + bv.w, 0.f);
    if (half == 0)
        ((float4*)out)[(size_t)node * 32 + sub] = o;
}

// F=16 gather-aggregate from f16 C: 8 lanes/node (4 x uint2, even/odd halves).
__global__ __launch_bounds__(256) void k_agg16(const __half* __restrict__ Ch, const unsigned int* __restrict__ csr,
                                               const int* __restrict__ offs, const float* __restrict__ dinv,
                                               const float* __restrict__ b, float* __restrict__ out, int n) {
    int t = blockIdx.x * 256 + threadIdx.x;
    int node = t >> 3;
    if (node >= n) return;
    int lane = t & 7;
    int sub  = lane & 3;      // uint2 (4 halves) within the 16-f row
    int half = lane >> 2;
    const uint2* C2 = (const uint2*)Ch;   // row stride = 4 uint2
    int ed = offs[node], end = offs[node + 1];
    float4 acc = make_float4(0.f, 0.f, 0.f, 0.f);

    #define EDGE_FMA16(P)                                                        \
        {                                                                        \
            uint2 q = C2[(size_t)((P) >> 16) * 4 + sub];                         \
            float w = __half2float(__ushort_as_half((unsigned short)((P) & 0xffffu))); \
            float2 f01 = __half22float2(*(const __half2*)&q.x);                  \
            float2 f23 = __half22float2(*(const __half2*)&q.y);                  \
            acc.x = fmaf(w, f01.x, acc.x); acc.y = fmaf(w, f01.y, acc.y);        \
            acc.z = fmaf(w, f23.x, acc.z); acc.w = fmaf(w, f23.y, acc.w);        \
        }

    for (; ed + 3 < end; ed += 4) {
        unsigned int p0 = csr[ed     + half];
        unsigned int p1 = csr[ed + 2 + half];
        EDGE_FMA16(p0); EDGE_FMA16(p1);
    }
    #pragma unroll
    for (int s = 0; s < 2; ++s) {          // tail: up to 3 edges
        int idx = ed + 2 * s + half;
        if (idx < end) {
            unsigned int p = csr[idx];
            EDGE_FMA16(p);
        }
    }
    #undef EDGE_FMA16

    acc.x += __shfl_xor(acc.x, 4);
    acc.y += __shfl_xor(acc.y, 4);
    acc.z += __shfl_xor(acc.z, 4);
    acc.w += __shfl_xor(acc.w, 4);

    float di = dinv[node], sl = di * di;
    uint2 qh = C2[(size_t)node * 4 + sub];
    float2 h01 = __half22float2(*(const __half2*)&qh.x);
    float2 h23 = __half22float2(*(const __half2*)&qh.y);
    float4 bv = ((const float4*)b)[sub];
    float4 o;
    o.x = fmaxf(fmaf(sl, h01.x, acc.x) + bv.x, 0.f);
    o.y = fmaxf(fmaf(sl, h01.y, acc.y) + bv.y, 0.f);
    o.z = fmaxf(fmaf(sl, h23.x, acc.z) + bv.z, 0.f);
    o.w = fmaxf(fmaf(sl, h23.y, acc.w) + bv.w, 0.f);
    if (half == 0)
        ((float4*)out)[(size_t)node * 4 + sub] = o;
}

extern "C" void kernel_launch(void* const* d_in, const int* in_sizes, int n_in,
                              void* d_out, int out_size, void* d_ws, size_t ws_size,
                              hipStream_t stream) {
    const float* x  = (const float*)d_in[0];
    const int*   ei = (const int*)d_in[1];
    const float* W1 = (const float*)d_in[2];
    const float* b1 = (const float*)d_in[3];
    const float* W2 = (const float*)d_in[4];
    const float* b2 = (const float*)d_in[5];
    const float* W3 = (const float*)d_in[6];
    const float* b3 = (const float*)d_in[7];

    const int n = in_sizes[0] / 128;   // 50000 (< 65536, required by packed CSR)
    const int e = in_sizes[1] / 2;
    const int* row = ei;       // source j
    const int* col = ei + e;   // target i

    unsigned int* csr = (unsigned int*)d_ws;
    __half* Ah  = (__half*)(csr + e);
    float*  B   = (float*)(Ah + (size_t)n * 128);
    __half* Ch  = (__half*)(B + (size_t)n * 128);
    float* dinv = (float*)(Ch + (size_t)n * 16);
    int*   offs = (int*)(dinv + n);
    int*   cnt  = offs + (n + 1);
    int*   cur  = cnt + n;
    int*   bsum = cur + n;
    float* out  = (float*)d_out;

    const int nb = cdiv(n + 1, 256);
    const int fillBlocks = 256;          // per replica; grid = 8 * 256

    // --- CSR build ---
    k_zero_int<<<cdiv(n, 256), 256, 0, stream>>>(cnt, n);
    k_count   <<<cdiv(e, 256), 256, 0, stream>>>(col, cnt, e);
    k_scanA   <<<nb, 256, 0, stream>>>(cnt, bsum, dinv, n);
    k_scanB   <<<1, 256, 0, stream>>>(bsum, nb);
    k_scanC   <<<nb, 256, 0, stream>>>(cnt, bsum, offs, cur, n);
    k_fill_xcd<<<8 * fillBlocks, 256, 0, stream>>>(row, col, dinv, cur, csr, e, n, fillBlocks);

    // --- layer 1 ---
    k_gemm128<<<cdiv(n, 128), 256, 0, stream>>>(x, W1, Ah, n);
    k_agg128 <<<cdiv(n * 64, 256), 256, 0, stream>>>(Ah, csr, offs, dinv, b1, B, n);
    // --- layer 2 ---
    k_gemm128<<<cdiv(n, 128), 256, 0, stream>>>(B, W2, Ah, n);
    k_agg128 <<<cdiv(n * 64, 256), 256, 0, stream>>>(Ah, csr, offs, dinv, b2, B, n);
    // --- layer 3 ---
    k_gemm16 <<<cdiv(n, 16), 256, 0, stream>>>(B, W3, Ch, n);
    k_agg16  <<<cdiv(n * 8, 256), 256, 0, stream>>>(Ch, csr, offs, dinv, b3, out, n);
}